// Round 13
// baseline (182.133 us; speedup 1.0000x reference)
//
#include <hip/hip_runtime.h>
#include <hip/hip_bf16.h>

#define B_ 2
#define T_ 2048
#define C_ 1024
#define H_ 16
#define D_ 64

typedef unsigned short u16;
typedef __bf16 bf16x8 __attribute__((ext_vector_type(8)));
typedef float floatx4 __attribute__((ext_vector_type(4)));

__device__ __forceinline__ float bf2f(u16 u) {
  union { unsigned int i; float f; } x; x.i = ((unsigned int)u) << 16; return x.f;
}
__device__ __forceinline__ u16 f2bf(float f) {  // RNE
  union { float f; unsigned int i; } x; x.f = f;
  unsigned int r = x.i + 0x7fffu + ((x.i >> 16) & 1u);
  return (u16)(r >> 16);
}

// packed f32x2 -> bf16x2 (RTNE), lo = src0
__device__ __forceinline__ unsigned cvtpk(float lo, float hi) {
  unsigned r;
  asm("v_cvt_pk_bf16_f32 %0, %1, %2" : "=v"(r) : "v"(lo), "v"(hi));
  return r;
}

// async 16B global -> LDS (wave-uniform base + lane*16)
__device__ __forceinline__ void gld16(void* lds, const void* g) {
  __builtin_amdgcn_global_load_lds(
      (const __attribute__((address_space(1))) unsigned int*)g,
      (__attribute__((address_space(3))) unsigned int*)lds, 16, 0, 0);
}

// ---------------------------------------------------------------------------
// Fused fp32 -> bf16 convert for x + 4 weights (one dispatch).
// ---------------------------------------------------------------------------
#define NXF4 1048576   // (B*T*C)/4
#define NWF4 262144    // (C*C)/4

__global__ __launch_bounds__(256) void cvt_all(
    const float* __restrict__ x,  const float* __restrict__ Wq,
    const float* __restrict__ Wk, const float* __restrict__ Wv,
    const float* __restrict__ Wo, u16* __restrict__ dst_base)
{
  const int i = blockIdx.x * 256 + threadIdx.x;
  const float* src; size_t off;
  if (i < NXF4)               { src = x;  off = i; }
  else if (i < NXF4 + NWF4)   { src = Wq; off = i - NXF4; }
  else if (i < NXF4 + 2*NWF4) { src = Wk; off = i - (NXF4 + NWF4); }
  else if (i < NXF4 + 3*NWF4) { src = Wv; off = i - (NXF4 + 2*NWF4); }
  else                        { src = Wo; off = i - (NXF4 + 3*NWF4); }
  float4 f = ((const float4*)src)[off];
  ushort4 o;
  o.x = f2bf(f.x); o.y = f2bf(f.y); o.z = f2bf(f.z); o.w = f2bf(f.w);
  ((ushort4*)dst_base)[i] = o;
}

// ---------------------------------------------------------------------------
// Fused QKV GEMM, 128x192 tile, BK=64, 4-phase counted-vmcnt schedule.
// Grid 512 = 2 blocks/CU (80 KB LDS each). r12-proven (180.8 us best).
// ---------------------------------------------------------------------------
#define QSCALE 0.1803368801111f  // 0.125 / ln(2)

#define PBAR()                                                \
  do {                                                        \
    asm volatile("" ::: "memory");                            \
    __builtin_amdgcn_s_barrier();                             \
    asm volatile("s_waitcnt lgkmcnt(0)" ::: "memory");        \
  } while (0)

#define EBAR()                                                \
  do {                                                        \
    asm volatile("" ::: "memory");                            \
    __builtin_amdgcn_s_barrier();                             \
    asm volatile("" ::: "memory");                            \
  } while (0)

__global__ __launch_bounds__(512, 4) void gemm_qkv8(
    const u16* __restrict__ X, const u16* __restrict__ Wb,
    const float* __restrict__ b0, const float* __restrict__ b1,
    const float* __restrict__ b2,
    u16* __restrict__ Yq, u16* __restrict__ Yk, u16* __restrict__ Yv)
{
  __shared__ __align__(16) u16 L[40960];  // 80 KiB

  const int tid  = threadIdx.x;
  const int lane = tid & 63;
  const int m16  = lane & 15;
  const int q4   = lane >> 4;
  const int wv   = tid >> 6;
  const int wm   = wv >> 2;   // 0..1 : 64-row A slab
  const int wn   = wv & 3;    // 0..3 : 48-col B slab

  // XCD-bijective: 512 blocks, 64/XCD as an 8x8 (bx,by) sub-grid
  const int bid = blockIdx.x;
  const int xcd = bid & 7;
  const int idx = bid >> 3;                     // 0..63
  const int bx  = (xcd & 3) * 8 + (idx & 7);    // 0..31
  const int by  = (xcd >> 2) * 8 + (idx >> 3);  // 0..15

  const u16* Abase = X  + (size_t)bx * 128 * C_;
  const u16* Bbase = Wb + (size_t)by * 192 * C_;

  const int rB  = tid >> 3;                 // 0..63
  const int k0a = ((tid & 7) ^ (rB & 7)) * 8;   // unit rows 64 ≡ 0 mod 8

#define STG_U(dst, srcrows, unit, kofs)                                       \
  gld16(&(dst)[((unit) * 512 + tid) * 8],                                     \
        (srcrows) + (size_t)((unit) * 64 + rB) * C_ + (kofs) + k0a)

  u16* buf0 = L;
  u16* buf1 = L + 20480;
  // per buffer (u16): A[128x64] @0 (8192), B[192x64] @8192 (12288)

  // prologue: T0 (5 ops) + T1 {B0,B1} (2 ops); wait T0 -> vmcnt(2)
  STG_U(buf0 + 8192, Bbase, 0, 0);
  STG_U(buf0 + 8192, Bbase, 1, 0);
  STG_U(buf0 + 8192, Bbase, 2, 0);
  STG_U(buf0,        Abase, 0, 0);
  STG_U(buf0,        Abase, 1, 0);
  STG_U(buf1 + 8192, Bbase, 0, 64);
  STG_U(buf1 + 8192, Bbase, 1, 64);
  asm volatile("s_waitcnt vmcnt(2)" ::: "memory");
  __builtin_amdgcn_s_barrier();
  asm volatile("" ::: "memory");

  floatx4 acc[4][3] = {};

  const int a0off = m16 * 64 + ((q4      ^ (lane & 7)) * 8);  // k-chunk 0
  const int a1off = m16 * 64 + (((q4 + 4) ^ (lane & 7)) * 8); // k-chunk 1
  const int aro   = wm * 4096;         // wave's 64-row A slab (64*64)
  const int bro   = 8192 + wn * 3072;  // wave's 48-row B slab (48*64)

  for (int i = 0; i < 16; ++i) {
    u16* buf  = (i & 1) ? buf1 : buf0;
    u16* bufn = (i & 1) ? buf0 : buf1;
    const bool p1 = (i + 1) < 16;
    const bool p2 = (i + 2) < 16;
    const int  k1 = (i + 1) * 64;
    const int  k2 = (i + 2) * 64;

    bf16x8 a[4][2], bA[2][2], bB[2];

    // ---- phase 0: (rf01, nf01) — 8 ds_reads, 8 MFMA ----
#pragma unroll
    for (int f = 0; f < 2; ++f) {
      a[f][0] = *(const bf16x8*)&buf[aro + f * 1024 + a0off];
      a[f][1] = *(const bf16x8*)&buf[aro + f * 1024 + a1off];
    }
#pragma unroll
    for (int g = 0; g < 2; ++g) {
      bA[g][0] = *(const bf16x8*)&buf[bro + g * 1024 + a0off];
      bA[g][1] = *(const bf16x8*)&buf[bro + g * 1024 + a1off];
    }
    if (p1) { STG_U(bufn, Abase, 0, k1); STG_U(bufn, Abase, 1, k1); }
    PBAR();
    __builtin_amdgcn_s_setprio(1);
#pragma unroll
    for (int f = 0; f < 2; ++f)
#pragma unroll
      for (int g = 0; g < 2; ++g) {
        acc[f][g] = __builtin_amdgcn_mfma_f32_16x16x32_bf16(a[f][0], bA[g][0], acc[f][g], 0, 0, 0);
        acc[f][g] = __builtin_amdgcn_mfma_f32_16x16x32_bf16(a[f][1], bA[g][1], acc[f][g], 0, 0, 0);
      }
    __builtin_amdgcn_s_setprio(0);
    EBAR();

    // ---- phase 1: (rf01, nf2) — 2 ds_reads, 4 MFMA ----
    bB[0] = *(const bf16x8*)&buf[bro + 2048 + a0off];
    bB[1] = *(const bf16x8*)&buf[bro + 2048 + a1off];
    if (p1) STG_U(bufn + 8192, Bbase, 2, k1);
    PBAR();
    __builtin_amdgcn_s_setprio(1);
#pragma unroll
    for (int f = 0; f < 2; ++f) {
      acc[f][2] = __builtin_amdgcn_mfma_f32_16x16x32_bf16(a[f][0], bB[0], acc[f][2], 0, 0, 0);
      acc[f][2] = __builtin_amdgcn_mfma_f32_16x16x32_bf16(a[f][1], bB[1], acc[f][2], 0, 0, 0);
    }
    __builtin_amdgcn_s_setprio(0);
    EBAR();

    // ---- phase 2: (rf23, nf2) — 4 ds_reads, 4 MFMA ----
#pragma unroll
    for (int f = 2; f < 4; ++f) {
      a[f][0] = *(const bf16x8*)&buf[aro + f * 1024 + a0off];
      a[f][1] = *(const bf16x8*)&buf[aro + f * 1024 + a1off];
    }
    if (p2) {   // B reads of this tile done (ph0+ph1)
      STG_U(buf + 8192, Bbase, 0, k2);
      STG_U(buf + 8192, Bbase, 1, k2);
    }
    PBAR();
    __builtin_amdgcn_s_setprio(1);
#pragma unroll
    for (int f = 2; f < 4; ++f) {
      acc[f][2] = __builtin_amdgcn_mfma_f32_16x16x32_bf16(a[f][0], bB[0], acc[f][2], 0, 0, 0);
      acc[f][2] = __builtin_amdgcn_mfma_f32_16x16x32_bf16(a[f][1], bB[1], acc[f][2], 0, 0, 0);
    }
    __builtin_amdgcn_s_setprio(0);
    EBAR();

    // ---- phase 3: (rf23, nf01) — regs only, 8 MFMA ----
    PBAR();
    __builtin_amdgcn_s_setprio(1);
#pragma unroll
    for (int f = 2; f < 4; ++f)
#pragma unroll
      for (int g = 0; g < 2; ++g) {
        acc[f][g] = __builtin_amdgcn_mfma_f32_16x16x32_bf16(a[f][0], bA[g][0], acc[f][g], 0, 0, 0);
        acc[f][g] = __builtin_amdgcn_mfma_f32_16x16x32_bf16(a[f][1], bA[g][1], acc[f][g], 0, 0, 0);
      }
    __builtin_amdgcn_s_setprio(0);
    asm volatile("" ::: "memory");
    if (p2) asm volatile("s_waitcnt vmcnt(2)" ::: "memory");
    else    asm volatile("s_waitcnt vmcnt(0)" ::: "memory");
    __builtin_amdgcn_s_barrier();
    asm volatile("" ::: "memory");
  }

  // ---- epilogue: V direct; Q/K via LDS transpose (L dead, 48KB tile) ----
  const int mbase = bx * 128 + wm * 64 + q4 * 4;
#pragma unroll
  for (int nf = 0; nf < 3; ++nf) {
    const int nzg = by * 192 + wn * 48 + nf * 16 + m16;
    const int z  = nzg >> 10;           // 0=Q 1=K 2=V (uniform in fragment)
    const int nl = nzg & 1023;
    if (z == 2) {
      const int h = nl >> 6, d = nl & (D_ - 1);
      const float bv = b2[nl];
#pragma unroll
      for (int rf = 0; rf < 4; ++rf) {
        const int m  = mbase + rf * 16;
        const int bb = m >> 11, t = m & (T_ - 1);
        ushort4 pk;
        pk.x = f2bf(acc[rf][nf][0] + bv);
        pk.y = f2bf(acc[rf][nf][1] + bv);
        pk.z = f2bf(acc[rf][nf][2] + bv);
        pk.w = f2bf(acc[rf][nf][3] + bv);
        *(ushort4*)&Yv[(((size_t)bb * H_ + h) * D_ + d) * T_ + t] = pk;
      }
    } else {
      const float bv = (z == 0 ? b0 : b1)[nl];
      const float sc = z ? 1.0f : QSCALE;
      const int c_loc = wn * 48 + nf * 16 + m16;
      const int chunk = c_loc >> 3, cl = c_loc & 7;
#pragma unroll
      for (int rf = 0; rf < 4; ++rf) {
#pragma unroll
        for (int r = 0; r < 4; ++r) {
          const int t_loc = wm * 64 + rf * 16 + q4 * 4 + r;
          const int pc = ((chunk & ~7) | ((chunk & 7) ^ (t_loc & 7))) * 8 + cl;
          L[t_loc * 192 + pc] = f2bf((acc[rf][nf][r] + bv) * sc);
        }
      }
    }
  }
  __syncthreads();
  // transpose-read: 3 x 64-col (z,h) groups x 2 row-passes, uint4 stores
  {
    const int row_off = tid >> 3;        // 0..63
    const int ch_off  = tid & 7;         // 0..7
#pragma unroll
    for (int gi = 0; gi < 3; ++gi) {
      const int gg = by * 3 + gi;        // 0..47
      const int z  = gg >> 4;
      if (z == 2) continue;
      u16* Y = z ? Yk : Yq;
      const int h = gg & 15;
#pragma unroll
      for (int pass = 0; pass < 2; ++pass) {
        const int t_loc = pass * 64 + row_off;
        const int pl3 = ch_off ^ (t_loc & 7);
        const uint4 val = *(const uint4*)&L[t_loc * 192 + (gi * 8 + pl3) * 8];
        const int m = bx * 128 + t_loc;
        const int bb = m >> 11, tq = m & (T_ - 1);
        *(uint4*)&Y[(((size_t)bb * H_ + h) * T_ + tq) * D_ + ch_off * 8] = val;
      }
    }
  }
}

// ---------------------------------------------------------------------------
// Output projection GEMM (r0-r4 proven): 128x64 tile, BK=32, grid (32,16)
// = 512 blocks = 2 blocks/CU. REVERTED from the r6 128x128/256-block retile:
// that config ran 1 block/CU — the occupancy failure mode r4/r12 proved
// costly (syncthreads-per-K-step needs a co-resident block to hide drains).
// ---------------------------------------------------------------------------
__global__ __launch_bounds__(256) void gemm_out(
    const u16* __restrict__ X, const u16* __restrict__ W,
    const float* __restrict__ bias, float* __restrict__ Yf)
{
  const int K = C_, N = C_;
  __shared__ __align__(16) u16 As[128 * 32];  // 8 KB
  __shared__ __align__(16) u16 Bs[64 * 32];   // 4 KB

  const int tid  = threadIdx.x;
  const int wv   = tid >> 6;
  const int lane = tid & 63;
  const int mcol = lane & 15;
  const int quad = lane >> 4;
  const int wr = wv >> 1, wc = wv & 1;
  const int m0 = blockIdx.x * 128;
  const int n0 = blockIdx.y * 64;

  const int srow = tid >> 2;
  const int scol = (tid & 3) * 8;
  const u16* xp0 = X + (size_t)(m0 + srow) * K + scol;
  const u16* xp1 = xp0 + (size_t)64 * K;
  const u16* wp  = W + (size_t)(n0 + srow) * K + scol;

  floatx4 acc[4][2] = {};

  for (int k0 = 0; k0 < K; k0 += 32) {
    gld16(&As[tid * 8],        xp0 + k0);
    gld16(&As[2048 + tid * 8], xp1 + k0);
    gld16(&Bs[tid * 8],        wp + k0);
    __syncthreads();

    bf16x8 a[4], b[2];
#pragma unroll
    for (int rf = 0; rf < 4; ++rf)
      a[rf] = *(const bf16x8*)&As[(wr * 64 + rf * 16 + mcol) * 32 + quad * 8];
#pragma unroll
    for (int cf = 0; cf < 2; ++cf)
      b[cf] = *(const bf16x8*)&Bs[(wc * 32 + cf * 16 + mcol) * 32 + quad * 8];
#pragma unroll
    for (int rf = 0; rf < 4; ++rf)
#pragma unroll
      for (int cf = 0; cf < 2; ++cf)
        acc[rf][cf] = __builtin_amdgcn_mfma_f32_16x16x32_bf16(
            a[rf], b[cf], acc[rf][cf], 0, 0, 0);
    __syncthreads();
  }

#pragma unroll
  for (int cf = 0; cf < 2; ++cf) {
    const int n = n0 + wc * 32 + cf * 16 + mcol;
    const float bv = bias[n];
#pragma unroll
    for (int rf = 0; rf < 4; ++rf) {
#pragma unroll
      for (int r = 0; r < 4; ++r) {
        const int m = m0 + wr * 64 + rf * 16 + quad * 4 + r;
        Yf[(size_t)m * N + n] = acc[rf][cf][r] + bv;
      }
    }
  }
}

// ---------------------------------------------------------------------------
// MFMA flash attention, QBLK=128 + k-split chunking, 3-deep K/V pipeline
// with counted vmcnt (r10-r12 structure, passed). Fixed-base log2 softmax,
// swapped QK^T, in-register P rebuild, vones register rowsum.
// ---------------------------------------------------------------------------
#define KSB 4096   // u16 elems per Ks buffer (64*64)
#define VTB 4096   // u16 elems per Vt buffer (64*64)

// 24 chunks/head: t, j-range, partial mode (0 direct, 1/2 partial half).
__constant__ unsigned char CH_T[24]  = {7,15,15,14,14,6,13,13, 4,10,10,5,11,11,12,12, 9,9,8,8,3,2,1,0};
__constant__ unsigned char CH_J0[24] = {0,0,16,0,15,0,0,14,   0,0,11,0,0,12,0,13,    0,10,0,9,0,0,0,0};
__constant__ unsigned char CH_J1[24] = {15,15,31,14,29,13,13,27, 9,10,21,11,11,23,12,25, 9,19,8,17,7,5,3,1};
__constant__ unsigned char CH_P[24]  = {0,1,2,1,2,0,1,2,      0,1,2,0,1,2,1,2,       1,2,1,2,0,0,0,0};

__global__ __launch_bounds__(256, 3) void attn_flash(
    const u16* __restrict__ Q, const u16* __restrict__ K,
    const u16* __restrict__ Vg, u16* __restrict__ O,
    float* __restrict__ OP, float* __restrict__ LP)
{
  __shared__ __align__(16) u16 Ks[3 * KSB];     // 24 KB
  __shared__ __align__(16) u16 Vt[3 * VTB];     // 24 KB

  const int tid  = threadIdx.x;
  const int wv   = tid >> 6;
  const int lane = tid & 63;
  const int mcol = lane & 15;
  const int quad = lane >> 4;

  const int bx = blockIdx.x;
  const int bh = bx & 31;             // XCD-partition invariant
  const int c  = bx >> 5;             // 0..23 chunk slot
  const int t  = CH_T[c];
  const int j0 = CH_J0[c];
  const int j1 = CH_J1[c];
  const int pm = CH_P[c];             // 0 direct, 1/2 partial half
  const int ti = pm ? ((bh * 8 + (t - 8)) * 2 + (pm - 1)) : 0;

  const size_t base  = (size_t)bh * T_ * D_;
  const size_t vbase = (size_t)bh * D_ * T_;
  const int b = bh >> 4, h = bh & (H_ - 1);

  // register-constant ones B-frag for the rowsum MFMA
  bf16x8 vones;
  {
    const u16 ov = (mcol == 0) ? (u16)0x3F80 : (u16)0;
    union { u16 s[8]; bf16x8 v; } tmp;
#pragma unroll
    for (int i = 0; i < 8; ++i) tmp.s[i] = ov;
    vones = tmp.v;
  }

  const int srow = lane >> 3;
  const int sg   = (lane & 7) ^ srow;
  const int c0 = wv * 2, c1 = wv * 2 + 1;
  const int sl0 = (quad ^ (mcol & 7)) * 8;

  const size_t koff0 = base + (size_t)(c0 * 8 + srow) * D_ + sg * 8;
  const size_t koff1 = base + (size_t)(c1 * 8 + srow) * D_ + sg * 8;
  const size_t voff0 = vbase + (size_t)(c0 * 8 + srow) * T_ + sg * 8;
  const size_t voff1 = vbase + (size_t)(c1 * 8 + srow) * T_ + sg * 8;

  // 32 q-rows per wave: halves at rows t*128 + wv*32 + {0,16} + mcol
  const u16* qg = Q + base + (size_t)(t * 128 + wv * 32 + mcol) * D_ + quad * 8;
  const bf16x8 qf[2][2] = {
    { *(const bf16x8*)qg,             *(const bf16x8*)(qg + 32) },
    { *(const bf16x8*)(qg + 16 * D_), *(const bf16x8*)(qg + 16 * D_ + 32) }
  };

  floatx4 oacc[2][5] = {};   // [half][0..3] D-cols; [half][4] rowsum

#define STG_KV(bufi, jt)                                                      \
  do {                                                                        \
    const size_t kj_ = (size_t)(jt) * 64 * D_;                                \
    const int    vj_ = (jt) * 64;                                             \
    gld16(&Ks[(bufi) * KSB + c0 * 512 + lane * 8], K  + koff0 + kj_);         \
    gld16(&Ks[(bufi) * KSB + c1 * 512 + lane * 8], K  + koff1 + kj_);         \
    gld16(&Vt[(bufi) * VTB + c0 * 512 + lane * 8], Vg + voff0 + vj_);         \
    gld16(&Vt[(bufi) * VTB + c1 * 512 + lane * 8], Vg + voff1 + vj_);         \
  } while (0)

  // prologue: stage j0 and j0+1 (8 gld16/wave in flight)
  STG_KV(0, j0);
  if (j0 + 1 <= j1) STG_KV(1, j0 + 1);

  int cur = 0;
  for (int j = j0; j <= j1; ++j) {
    // counted wait: tile j's 4 ops retired; tile j+1's stay in flight
    asm volatile("" ::: "memory");
    if (j < j1) asm volatile("s_waitcnt vmcnt(4)" ::: "memory");
    else        asm volatile("s_waitcnt vmcnt(0)" ::: "memory");
    __builtin_amdgcn_s_barrier();
    asm volatile("" ::: "memory");

    if (j + 2 <= j1) {     // stage j+2 into tile j-1's buffer (safe: barrier)
      int nb = cur + 2; if (nb >= 3) nb -= 3;
      STG_KV(nb, j + 2);
    }

    const u16* ksb = &Ks[cur * KSB];
    const u16* vtb = &Vt[cur * VTB];

    // SWAPPED QK^T: sacc[hf][nt][r] = S[q = mcol + hf*16 + wv*32][
    // k = nt*16 + quad*4 + r]; K frags read once, used by both halves.
    floatx4 sacc[2][4] = {};
    __builtin_amdgcn_s_setprio(1);
#pragma unroll
    for (int nt = 0; nt < 4; ++nt) {
      const u16* kr = &ksb[(nt * 16 + mcol) * 64];
      bf16x8 kb0 = *(const bf16x8*)&kr[sl0];
      bf16x8 kb1 = *(const bf16x8*)&kr[sl0 ^ 32];
      sacc[0][nt] = __builtin_amdgcn_mfma_f32_16x16x32_bf16(kb0, qf[0][0], sacc[0][nt], 0, 0, 0);
      sacc[0][nt] = __builtin_amdgcn_mfma_f32_16x16x32_bf16(kb1, qf[0][1], sacc[0][nt], 0, 0, 0);
      sacc[1][nt] = __builtin_amdgcn_mfma_f32_16x16x32_bf16(kb0, qf[1][0], sacc[1][nt], 0, 0, 0);
      sacc[1][nt] = __builtin_amdgcn_mfma_f32_16x16x32_bf16(kb1, qf[1][1], sacc[1][nt], 0, 0, 0);
    }
    __builtin_amdgcn_s_setprio(0);

    const int dj = j - 2 * t;
    if (dj >= 0) {     // causal mask on the two diagonal k-tiles
#pragma unroll
      for (int hf = 0; hf < 2; ++hf) {
        const int klim = wv * 32 + hf * 16 + mcol - dj * 64;
#pragma unroll
        for (int nt = 0; nt < 4; ++nt)
#pragma unroll
          for (int r = 0; r < 4; ++r)
            if (nt * 16 + quad * 4 + r > klim) sacc[hf][nt][r] = -1e30f;
      }
    }

    // exp2 + pack + in-register redistribute -> PV A-frags (per half)
    bf16x8 pa[2][2];
#pragma unroll
    for (int hf = 0; hf < 2; ++hf) {
      unsigned w[4][2];
#pragma unroll
      for (int nt = 0; nt < 4; ++nt)
#pragma unroll
        for (int i = 0; i < 2; ++i)
          w[nt][i] = cvtpk(exp2f(sacc[hf][nt][2*i]), exp2f(sacc[hf][nt][2*i+1]));
      union { unsigned u[4]; bf16x8 v; } p0, p1;
#pragma unroll
      for (int i = 0; i < 2; ++i) {
        unsigned x = w[0][i], y = w[1][i];
        asm("v_permlane32_swap_b32 %0, %1" : "+v"(x), "+v"(y));
        asm("v_permlane16_swap_b32 %0, %1" : "+v"(x), "+v"(y));
        p0.u[i] = x; p0.u[i + 2] = y;
        unsigned x2 = w[2][i], y2 = w[3][i];
        asm("v_permlane32_swap_b32 %0, %1" : "+v"(x2), "+v"(y2));
        asm("v_permlane16_swap_b32 %0, %1" : "+v"(x2), "+v"(y2));
        p1.u[i] = x2; p1.u[i + 2] = y2;
      }
      pa[hf][0] = p0.v; pa[hf][1] = p1.v;
    }

    __builtin_amdgcn_s_setprio(1);
#pragma unroll
    for (int dt = 0; dt < 4; ++dt) {
      const u16* vr = &vtb[(dt * 16 + mcol) * 64];
      bf16x8 vb0 = *(const bf16x8*)&vr[sl0];
      bf16x8 vb1 = *(const bf16x8*)&vr[sl0 ^ 32];
      oacc[0][dt] = __builtin_amdgcn_mfma_f32_16x16x32_bf16(pa[0][0], vb0, oacc[0][dt], 0, 0, 0);
      oacc[0][dt] = __builtin_amdgcn_mfma_f32_16x16x32_bf16(pa[0][1], vb1, oacc[0][dt], 0, 0, 0);
      oacc[1][dt] = __builtin_amdgcn_mfma_f32_16x16x32_bf16(pa[1][0], vb0, oacc[1][dt], 0, 0, 0);
      oacc[1][dt] = __builtin_amdgcn_mfma_f32_16x16x32_bf16(pa[1][1], vb1, oacc[1][dt], 0, 0, 0);
    }
    // rowsum slots: constant ones B-frag (no LDS reads)
    oacc[0][4] = __builtin_amdgcn_mfma_f32_16x16x32_bf16(pa[0][0], vones, oacc[0][4], 0, 0, 0);
    oacc[0][4] = __builtin_amdgcn_mfma_f32_16x16x32_bf16(pa[0][1], vones, oacc[0][4], 0, 0, 0);
    oacc[1][4] = __builtin_amdgcn_mfma_f32_16x16x32_bf16(pa[1][0], vones, oacc[1][4], 0, 0, 0);
    oacc[1][4] = __builtin_amdgcn_mfma_f32_16x16x32_bf16(pa[1][1], vones, oacc[1][4], 0, 0, 0);
    __builtin_amdgcn_s_setprio(0);

    cur = (cur == 2) ? 0 : cur + 1;
  }

  if (!pm) {
    // direct store (unsplit tiles, t < 8)
#pragma unroll
    for (int hf = 0; hf < 2; ++hf) {
      float invl[4];
#pragma unroll
      for (int r = 0; r < 4; ++r)
        invl[r] = 1.f / __shfl(oacc[hf][4][r], lane & 48);
#pragma unroll
      for (int dt = 0; dt < 4; ++dt) {
        const int cc = h * D_ + dt * 16 + mcol;
#pragma unroll
        for (int r = 0; r < 4; ++r) {
          const int tg = t * 128 + wv * 32 + hf * 16 + quad * 4 + r;
          O[((size_t)b * T_ + tg) * C_ + cc] = f2bf(oacc[hf][dt][r] * invl[r]);
        }
      }
    }
  } else {
    // partial store: unnormalized f32 O (128x64) + l (pure-add merge later)
    float* op = OP + (size_t)ti * 8192;
#pragma unroll
    for (int hf = 0; hf < 2; ++hf) {
#pragma unroll
      for (int dt = 0; dt < 4; ++dt)
#pragma unroll
        for (int r = 0; r < 4; ++r)
          op[(wv * 32 + hf * 16 + quad * 4 + r) * 64 + dt * 16 + mcol] = oacc[hf][dt][r];
      if (mcol == 0) {
#pragma unroll
        for (int r = 0; r < 4; ++r)
          LP[ti * 128 + wv * 32 + hf * 16 + quad * 4 + r] = oacc[hf][4][r];
      }
    }
  }
}

// ---------------------------------------------------------------------------
// Merge the two k-chunks of each split q-tile (t = 8..15): O = (A+B)/(lA+lB).
// Grid 256 (32 bh x 8 tiles), 256 threads; thread = (row, 32-d-chunk).
// ---------------------------------------------------------------------------
__global__ __launch_bounds__(256) void attn_merge(
    const float* __restrict__ OP, const float* __restrict__ LP,
    u16* __restrict__ O)
{
  const int mb = blockIdx.x;
  const int bh = mb & 31, tt = mb >> 5;     // tt 0..7 -> t = 8+tt
  const int t = 8 + tt;
  const int ti0 = (bh * 8 + tt) * 2;
  const int b = bh >> 4, h = bh & (H_ - 1);
  const int row = threadIdx.x >> 1;         // 0..127
  const int dc  = (threadIdx.x & 1) * 32;

  const float l = LP[ti0 * 128 + row] + LP[(ti0 + 1) * 128 + row];
  const float inv = 1.f / l;
  const float* pa = OP + (size_t)ti0 * 8192 + row * 64 + dc;
  const float* pb = pa + 8192;

  const int tg = t * 128 + row;
  u16* o = O + ((size_t)b * T_ + tg) * C_ + h * D_ + dc;

  u16 tmp[32];
#pragma unroll
  for (int i = 0; i < 8; ++i) {
    const float4 a4 = ((const float4*)pa)[i];
    const float4 b4 = ((const float4*)pb)[i];
    tmp[i*4 + 0] = f2bf((a4.x + b4.x) * inv);
    tmp[i*4 + 1] = f2bf((a4.y + b4.y) * inv);
    tmp[i*4 + 2] = f2bf((a4.z + b4.z) * inv);
    tmp[i*4 + 3] = f2bf((a4.w + b4.w) * inv);
  }
#pragma unroll
  for (int i = 0; i < 4; ++i)
    ((uint4*)o)[i] = ((const uint4*)tmp)[i];
}

// ---------------------------------------------------------------------------
extern "C" void kernel_launch(void* const* d_in, const int* in_sizes, int n_in,
                              void* d_out, int out_size, void* d_ws, size_t ws_size,
                              hipStream_t stream) {
  const float* x  = (const float*)d_in[0];
  const float* Wq = (const float*)d_in[1];
  const float* bq = (const float*)d_in[2];
  const float* Wk = (const float*)d_in[3];
  const float* bk = (const float*)d_in[4];
  const float* Wv = (const float*)d_in[5];
  const float* bv = (const float*)d_in[6];
  const float* Wo = (const float*)d_in[7];
  const float* bo = (const float*)d_in[8];
  float* out = (float*)d_out;

  const size_t NX = (size_t)B_ * T_ * C_;  // 4M
  const size_t NW = (size_t)C_ * C_;       // 1M

  u16* xb  = (u16*)d_ws;
  u16* wqb = xb  + NX;        // weights contiguous (qkv GEMM indexes by z)
  u16* wkb = wqb + NW;
  u16* wvb = wkb + NW;
  u16* wob = wvb + NW;
  u16* q   = wob + NW;        // [B,H,T,D], pre-scaled log2-domain
  u16* k   = q   + NX;        // [B,H,T,D]
  u16* v   = k   + NX;        // [B,H,D,T]
  u16* ctx = v   + NX;        // [B,T,C]
  float* opart = (float*)(ctx + NX);           // 512 x 128x64 f32 = 16.8 MB
  float* lpart = opart + (size_t)512 * 8192;   // 512 x 128 f32

  cvt_all<<<dim3((NXF4 + 4 * NWF4) / 256), 256, 0, stream>>>(x, Wq, Wk, Wv, Wo, xb);

  gemm_qkv8<<<dim3(512), 512, 0, stream>>>(xb, wqb, bq, bk, bv, q, k, v);

  attn_flash<<<dim3(768), 256, 0, stream>>>(q, k, v, ctx, opart, lpart);

  attn_merge<<<dim3(256), 256, 0, stream>>>(opart, lpart, ctx);

  gemm_out<<<dim3(32, 16), 256, 0, stream>>>(ctx, wob, bo, out);
}

// Round 14
// 180.733 us; speedup vs baseline: 1.0077x; 1.0077x over previous
//
#include <hip/hip_runtime.h>
#include <hip/hip_bf16.h>

#define B_ 2
#define T_ 2048
#define C_ 1024
#define H_ 16
#define D_ 64

typedef unsigned short u16;
typedef __bf16 bf16x8 __attribute__((ext_vector_type(8)));
typedef float floatx4 __attribute__((ext_vector_type(4)));

__device__ __forceinline__ float bf2f(u16 u) {
  union { unsigned int i; float f; } x; x.i = ((unsigned int)u) << 16; return x.f;
}
__device__ __forceinline__ u16 f2bf(float f) {  // RNE
  union { float f; unsigned int i; } x; x.f = f;
  unsigned int r = x.i + 0x7fffu + ((x.i >> 16) & 1u);
  return (u16)(r >> 16);
}

// packed f32x2 -> bf16x2 (RTNE), lo = src0
__device__ __forceinline__ unsigned cvtpk(float lo, float hi) {
  unsigned r;
  asm("v_cvt_pk_bf16_f32 %0, %1, %2" : "=v"(r) : "v"(lo), "v"(hi));
  return r;
}

// async 16B global -> LDS (wave-uniform base + lane*16)
__device__ __forceinline__ void gld16(void* lds, const void* g) {
  __builtin_amdgcn_global_load_lds(
      (const __attribute__((address_space(1))) unsigned int*)g,
      (__attribute__((address_space(3))) unsigned int*)lds, 16, 0, 0);
}

// ---------------------------------------------------------------------------
// Fused fp32 -> bf16 convert for x + 4 weights (one dispatch).
// ---------------------------------------------------------------------------
#define NXF4 1048576   // (B*T*C)/4
#define NWF4 262144    // (C*C)/4

__global__ __launch_bounds__(256) void cvt_all(
    const float* __restrict__ x,  const float* __restrict__ Wq,
    const float* __restrict__ Wk, const float* __restrict__ Wv,
    const float* __restrict__ Wo, u16* __restrict__ dst_base)
{
  const int i = blockIdx.x * 256 + threadIdx.x;
  const float* src; size_t off;
  if (i < NXF4)               { src = x;  off = i; }
  else if (i < NXF4 + NWF4)   { src = Wq; off = i - NXF4; }
  else if (i < NXF4 + 2*NWF4) { src = Wk; off = i - (NXF4 + NWF4); }
  else if (i < NXF4 + 3*NWF4) { src = Wv; off = i - (NXF4 + 2*NWF4); }
  else                        { src = Wo; off = i - (NXF4 + 3*NWF4); }
  float4 f = ((const float4*)src)[off];
  ushort4 o;
  o.x = f2bf(f.x); o.y = f2bf(f.y); o.z = f2bf(f.z); o.w = f2bf(f.w);
  ((ushort4*)dst_base)[i] = o;
}

// ---------------------------------------------------------------------------
// Fused QKV GEMM, 128x192 tile, BK=64, 4-phase counted-vmcnt schedule.
// Grid 512 = 2 blocks/CU (80 KB LDS each). r12-proven (180.8 us best).
// ---------------------------------------------------------------------------
#define QSCALE 0.1803368801111f  // 0.125 / ln(2)

#define PBAR()                                                \
  do {                                                        \
    asm volatile("" ::: "memory");                            \
    __builtin_amdgcn_s_barrier();                             \
    asm volatile("s_waitcnt lgkmcnt(0)" ::: "memory");        \
  } while (0)

#define EBAR()                                                \
  do {                                                        \
    asm volatile("" ::: "memory");                            \
    __builtin_amdgcn_s_barrier();                             \
    asm volatile("" ::: "memory");                            \
  } while (0)

__global__ __launch_bounds__(512, 4) void gemm_qkv8(
    const u16* __restrict__ X, const u16* __restrict__ Wb,
    const float* __restrict__ b0, const float* __restrict__ b1,
    const float* __restrict__ b2,
    u16* __restrict__ Yq, u16* __restrict__ Yk, u16* __restrict__ Yv)
{
  __shared__ __align__(16) u16 L[40960];  // 80 KiB

  const int tid  = threadIdx.x;
  const int lane = tid & 63;
  const int m16  = lane & 15;
  const int q4   = lane >> 4;
  const int wv   = tid >> 6;
  const int wm   = wv >> 2;   // 0..1 : 64-row A slab
  const int wn   = wv & 3;    // 0..3 : 48-col B slab

  // XCD-bijective: 512 blocks, 64/XCD as an 8x8 (bx,by) sub-grid
  const int bid = blockIdx.x;
  const int xcd = bid & 7;
  const int idx = bid >> 3;                     // 0..63
  const int bx  = (xcd & 3) * 8 + (idx & 7);    // 0..31
  const int by  = (xcd >> 2) * 8 + (idx >> 3);  // 0..15

  const u16* Abase = X  + (size_t)bx * 128 * C_;
  const u16* Bbase = Wb + (size_t)by * 192 * C_;

  const int rB  = tid >> 3;                 // 0..63
  const int k0a = ((tid & 7) ^ (rB & 7)) * 8;   // unit rows 64 ≡ 0 mod 8

#define STG_U(dst, srcrows, unit, kofs)                                       \
  gld16(&(dst)[((unit) * 512 + tid) * 8],                                     \
        (srcrows) + (size_t)((unit) * 64 + rB) * C_ + (kofs) + k0a)

  u16* buf0 = L;
  u16* buf1 = L + 20480;
  // per buffer (u16): A[128x64] @0 (8192), B[192x64] @8192 (12288)

  // prologue: T0 (5 ops) + T1 {B0,B1} (2 ops); wait T0 -> vmcnt(2)
  STG_U(buf0 + 8192, Bbase, 0, 0);
  STG_U(buf0 + 8192, Bbase, 1, 0);
  STG_U(buf0 + 8192, Bbase, 2, 0);
  STG_U(buf0,        Abase, 0, 0);
  STG_U(buf0,        Abase, 1, 0);
  STG_U(buf1 + 8192, Bbase, 0, 64);
  STG_U(buf1 + 8192, Bbase, 1, 64);
  asm volatile("s_waitcnt vmcnt(2)" ::: "memory");
  __builtin_amdgcn_s_barrier();
  asm volatile("" ::: "memory");

  floatx4 acc[4][3] = {};

  const int a0off = m16 * 64 + ((q4      ^ (lane & 7)) * 8);  // k-chunk 0
  const int a1off = m16 * 64 + (((q4 + 4) ^ (lane & 7)) * 8); // k-chunk 1
  const int aro   = wm * 4096;         // wave's 64-row A slab (64*64)
  const int bro   = 8192 + wn * 3072;  // wave's 48-row B slab (48*64)

  for (int i = 0; i < 16; ++i) {
    u16* buf  = (i & 1) ? buf1 : buf0;
    u16* bufn = (i & 1) ? buf0 : buf1;
    const bool p1 = (i + 1) < 16;
    const bool p2 = (i + 2) < 16;
    const int  k1 = (i + 1) * 64;
    const int  k2 = (i + 2) * 64;

    bf16x8 a[4][2], bA[2][2], bB[2];

    // ---- phase 0: (rf01, nf01) — 8 ds_reads, 8 MFMA ----
#pragma unroll
    for (int f = 0; f < 2; ++f) {
      a[f][0] = *(const bf16x8*)&buf[aro + f * 1024 + a0off];
      a[f][1] = *(const bf16x8*)&buf[aro + f * 1024 + a1off];
    }
#pragma unroll
    for (int g = 0; g < 2; ++g) {
      bA[g][0] = *(const bf16x8*)&buf[bro + g * 1024 + a0off];
      bA[g][1] = *(const bf16x8*)&buf[bro + g * 1024 + a1off];
    }
    if (p1) { STG_U(bufn, Abase, 0, k1); STG_U(bufn, Abase, 1, k1); }
    PBAR();
    __builtin_amdgcn_s_setprio(1);
#pragma unroll
    for (int f = 0; f < 2; ++f)
#pragma unroll
      for (int g = 0; g < 2; ++g) {
        acc[f][g] = __builtin_amdgcn_mfma_f32_16x16x32_bf16(a[f][0], bA[g][0], acc[f][g], 0, 0, 0);
        acc[f][g] = __builtin_amdgcn_mfma_f32_16x16x32_bf16(a[f][1], bA[g][1], acc[f][g], 0, 0, 0);
      }
    __builtin_amdgcn_s_setprio(0);
    EBAR();

    // ---- phase 1: (rf01, nf2) — 2 ds_reads, 4 MFMA ----
    bB[0] = *(const bf16x8*)&buf[bro + 2048 + a0off];
    bB[1] = *(const bf16x8*)&buf[bro + 2048 + a1off];
    if (p1) STG_U(bufn + 8192, Bbase, 2, k1);
    PBAR();
    __builtin_amdgcn_s_setprio(1);
#pragma unroll
    for (int f = 0; f < 2; ++f) {
      acc[f][2] = __builtin_amdgcn_mfma_f32_16x16x32_bf16(a[f][0], bB[0], acc[f][2], 0, 0, 0);
      acc[f][2] = __builtin_amdgcn_mfma_f32_16x16x32_bf16(a[f][1], bB[1], acc[f][2], 0, 0, 0);
    }
    __builtin_amdgcn_s_setprio(0);
    EBAR();

    // ---- phase 2: (rf23, nf2) — 4 ds_reads, 4 MFMA ----
#pragma unroll
    for (int f = 2; f < 4; ++f) {
      a[f][0] = *(const bf16x8*)&buf[aro + f * 1024 + a0off];
      a[f][1] = *(const bf16x8*)&buf[aro + f * 1024 + a1off];
    }
    if (p2) {   // B reads of this tile done (ph0+ph1)
      STG_U(buf + 8192, Bbase, 0, k2);
      STG_U(buf + 8192, Bbase, 1, k2);
    }
    PBAR();
    __builtin_amdgcn_s_setprio(1);
#pragma unroll
    for (int f = 2; f < 4; ++f) {
      acc[f][2] = __builtin_amdgcn_mfma_f32_16x16x32_bf16(a[f][0], bB[0], acc[f][2], 0, 0, 0);
      acc[f][2] = __builtin_amdgcn_mfma_f32_16x16x32_bf16(a[f][1], bB[1], acc[f][2], 0, 0, 0);
    }
    __builtin_amdgcn_s_setprio(0);
    EBAR();

    // ---- phase 3: (rf23, nf01) — regs only, 8 MFMA ----
    PBAR();
    __builtin_amdgcn_s_setprio(1);
#pragma unroll
    for (int f = 2; f < 4; ++f)
#pragma unroll
      for (int g = 0; g < 2; ++g) {
        acc[f][g] = __builtin_amdgcn_mfma_f32_16x16x32_bf16(a[f][0], bA[g][0], acc[f][g], 0, 0, 0);
        acc[f][g] = __builtin_amdgcn_mfma_f32_16x16x32_bf16(a[f][1], bA[g][1], acc[f][g], 0, 0, 0);
      }
    __builtin_amdgcn_s_setprio(0);
    asm volatile("" ::: "memory");
    if (p2) asm volatile("s_waitcnt vmcnt(2)" ::: "memory");
    else    asm volatile("s_waitcnt vmcnt(0)" ::: "memory");
    __builtin_amdgcn_s_barrier();
    asm volatile("" ::: "memory");
  }

  // ---- epilogue: V direct; Q/K via LDS transpose (L dead, 48KB tile) ----
  const int mbase = bx * 128 + wm * 64 + q4 * 4;
#pragma unroll
  for (int nf = 0; nf < 3; ++nf) {
    const int nzg = by * 192 + wn * 48 + nf * 16 + m16;
    const int z  = nzg >> 10;           // 0=Q 1=K 2=V (uniform in fragment)
    const int nl = nzg & 1023;
    if (z == 2) {
      const int h = nl >> 6, d = nl & (D_ - 1);
      const float bv = b2[nl];
#pragma unroll
      for (int rf = 0; rf < 4; ++rf) {
        const int m  = mbase + rf * 16;
        const int bb = m >> 11, t = m & (T_ - 1);
        ushort4 pk;
        pk.x = f2bf(acc[rf][nf][0] + bv);
        pk.y = f2bf(acc[rf][nf][1] + bv);
        pk.z = f2bf(acc[rf][nf][2] + bv);
        pk.w = f2bf(acc[rf][nf][3] + bv);
        *(ushort4*)&Yv[(((size_t)bb * H_ + h) * D_ + d) * T_ + t] = pk;
      }
    } else {
      const float bv = (z == 0 ? b0 : b1)[nl];
      const float sc = z ? 1.0f : QSCALE;
      const int c_loc = wn * 48 + nf * 16 + m16;
      const int chunk = c_loc >> 3, cl = c_loc & 7;
#pragma unroll
      for (int rf = 0; rf < 4; ++rf) {
#pragma unroll
        for (int r = 0; r < 4; ++r) {
          const int t_loc = wm * 64 + rf * 16 + q4 * 4 + r;
          const int pc = ((chunk & ~7) | ((chunk & 7) ^ (t_loc & 7))) * 8 + cl;
          L[t_loc * 192 + pc] = f2bf((acc[rf][nf][r] + bv) * sc);
        }
      }
    }
  }
  __syncthreads();
  // transpose-read: 3 x 64-col (z,h) groups x 2 row-passes, uint4 stores
  {
    const int row_off = tid >> 3;        // 0..63
    const int ch_off  = tid & 7;         // 0..7
#pragma unroll
    for (int gi = 0; gi < 3; ++gi) {
      const int gg = by * 3 + gi;        // 0..47
      const int z  = gg >> 4;
      if (z == 2) continue;
      u16* Y = z ? Yk : Yq;
      const int h = gg & 15;
#pragma unroll
      for (int pass = 0; pass < 2; ++pass) {
        const int t_loc = pass * 64 + row_off;
        const int pl3 = ch_off ^ (t_loc & 7);
        const uint4 val = *(const uint4*)&L[t_loc * 192 + (gi * 8 + pl3) * 8];
        const int m = bx * 128 + t_loc;
        const int bb = m >> 11, tq = m & (T_ - 1);
        *(uint4*)&Y[(((size_t)bb * H_ + h) * T_ + tq) * D_ + ch_off * 8] = val;
      }
    }
  }
}

// ---------------------------------------------------------------------------
// Output projection GEMM (r12-best): 128x128 tile, BK=32, grid (32,8)
// = 256 blocks. (r13 A/B: the 128x64/512-block variant measured 182.1 vs
// this config's 180.8 — keep the r12 version.)
// ---------------------------------------------------------------------------
__global__ __launch_bounds__(256) void gemm_out(
    const u16* __restrict__ X, const u16* __restrict__ W,
    const float* __restrict__ bias, float* __restrict__ Yf)
{
  const int K = C_, N = C_;
  __shared__ __align__(16) u16 As[128 * 32];  // 8 KB
  __shared__ __align__(16) u16 Bs[128 * 32];  // 8 KB

  const int tid  = threadIdx.x;
  const int wv   = tid >> 6;
  const int lane = tid & 63;
  const int mcol = lane & 15;
  const int quad = lane >> 4;
  const int wr = wv >> 1, wc = wv & 1;
  const int m0 = blockIdx.x * 128;
  const int n0 = blockIdx.y * 128;

  const int srow = tid >> 2;
  const int scol = (tid & 3) * 8;
  const u16* xp0 = X + (size_t)(m0 + srow) * K + scol;
  const u16* xp1 = xp0 + (size_t)64 * K;
  const u16* wp0 = W + (size_t)(n0 + srow) * K + scol;
  const u16* wp1 = wp0 + (size_t)64 * K;

  floatx4 acc[4][4] = {};

  for (int k0 = 0; k0 < K; k0 += 32) {
    gld16(&As[tid * 8],        xp0 + k0);
    gld16(&As[2048 + tid * 8], xp1 + k0);
    gld16(&Bs[tid * 8],        wp0 + k0);
    gld16(&Bs[2048 + tid * 8], wp1 + k0);
    __syncthreads();

    bf16x8 a[4], b[4];
#pragma unroll
    for (int rf = 0; rf < 4; ++rf)
      a[rf] = *(const bf16x8*)&As[(wr * 64 + rf * 16 + mcol) * 32 + quad * 8];
#pragma unroll
    for (int cf = 0; cf < 4; ++cf)
      b[cf] = *(const bf16x8*)&Bs[(wc * 64 + cf * 16 + mcol) * 32 + quad * 8];
#pragma unroll
    for (int rf = 0; rf < 4; ++rf)
#pragma unroll
      for (int cf = 0; cf < 4; ++cf)
        acc[rf][cf] = __builtin_amdgcn_mfma_f32_16x16x32_bf16(
            a[rf], b[cf], acc[rf][cf], 0, 0, 0);
    __syncthreads();
  }

#pragma unroll
  for (int cf = 0; cf < 4; ++cf) {
    const int n = n0 + wc * 64 + cf * 16 + mcol;
    const float bv = bias[n];
#pragma unroll
    for (int rf = 0; rf < 4; ++rf) {
#pragma unroll
      for (int r = 0; r < 4; ++r) {
        const int m = m0 + wr * 64 + rf * 16 + quad * 4 + r;
        Yf[(size_t)m * N + n] = acc[rf][cf][r] + bv;
      }
    }
  }
}

// ---------------------------------------------------------------------------
// MFMA flash attention, QBLK=128 + k-split chunking, 3-deep K/V pipeline
// with counted vmcnt (r10-r12 structure, passed). Fixed-base log2 softmax,
// swapped QK^T, in-register P rebuild, vones register rowsum.
// ---------------------------------------------------------------------------
#define KSB 4096   // u16 elems per Ks buffer (64*64)
#define VTB 4096   // u16 elems per Vt buffer (64*64)

// 24 chunks/head: t, j-range, partial mode (0 direct, 1/2 partial half).
__constant__ unsigned char CH_T[24]  = {7,15,15,14,14,6,13,13, 4,10,10,5,11,11,12,12, 9,9,8,8,3,2,1,0};
__constant__ unsigned char CH_J0[24] = {0,0,16,0,15,0,0,14,   0,0,11,0,0,12,0,13,    0,10,0,9,0,0,0,0};
__constant__ unsigned char CH_J1[24] = {15,15,31,14,29,13,13,27, 9,10,21,11,11,23,12,25, 9,19,8,17,7,5,3,1};
__constant__ unsigned char CH_P[24]  = {0,1,2,1,2,0,1,2,      0,1,2,0,1,2,1,2,       1,2,1,2,0,0,0,0};

__global__ __launch_bounds__(256, 3) void attn_flash(
    const u16* __restrict__ Q, const u16* __restrict__ K,
    const u16* __restrict__ Vg, u16* __restrict__ O,
    float* __restrict__ OP, float* __restrict__ LP)
{
  __shared__ __align__(16) u16 Ks[3 * KSB];     // 24 KB
  __shared__ __align__(16) u16 Vt[3 * VTB];     // 24 KB

  const int tid  = threadIdx.x;
  const int wv   = tid >> 6;
  const int lane = tid & 63;
  const int mcol = lane & 15;
  const int quad = lane >> 4;

  const int bx = blockIdx.x;
  const int bh = bx & 31;             // XCD-partition invariant
  const int c  = bx >> 5;             // 0..23 chunk slot
  const int t  = CH_T[c];
  const int j0 = CH_J0[c];
  const int j1 = CH_J1[c];
  const int pm = CH_P[c];             // 0 direct, 1/2 partial half
  const int ti = pm ? ((bh * 8 + (t - 8)) * 2 + (pm - 1)) : 0;

  const size_t base  = (size_t)bh * T_ * D_;
  const size_t vbase = (size_t)bh * D_ * T_;
  const int b = bh >> 4, h = bh & (H_ - 1);

  // register-constant ones B-frag for the rowsum MFMA
  bf16x8 vones;
  {
    const u16 ov = (mcol == 0) ? (u16)0x3F80 : (u16)0;
    union { u16 s[8]; bf16x8 v; } tmp;
#pragma unroll
    for (int i = 0; i < 8; ++i) tmp.s[i] = ov;
    vones = tmp.v;
  }

  const int srow = lane >> 3;
  const int sg   = (lane & 7) ^ srow;
  const int c0 = wv * 2, c1 = wv * 2 + 1;
  const int sl0 = (quad ^ (mcol & 7)) * 8;

  const size_t koff0 = base + (size_t)(c0 * 8 + srow) * D_ + sg * 8;
  const size_t koff1 = base + (size_t)(c1 * 8 + srow) * D_ + sg * 8;
  const size_t voff0 = vbase + (size_t)(c0 * 8 + srow) * T_ + sg * 8;
  const size_t voff1 = vbase + (size_t)(c1 * 8 + srow) * T_ + sg * 8;

  // 32 q-rows per wave: halves at rows t*128 + wv*32 + {0,16} + mcol
  const u16* qg = Q + base + (size_t)(t * 128 + wv * 32 + mcol) * D_ + quad * 8;
  const bf16x8 qf[2][2] = {
    { *(const bf16x8*)qg,             *(const bf16x8*)(qg + 32) },
    { *(const bf16x8*)(qg + 16 * D_), *(const bf16x8*)(qg + 16 * D_ + 32) }
  };

  floatx4 oacc[2][5] = {};   // [half][0..3] D-cols; [half][4] rowsum

#define STG_KV(bufi, jt)                                                      \
  do {                                                                        \
    const size_t kj_ = (size_t)(jt) * 64 * D_;                                \
    const int    vj_ = (jt) * 64;                                             \
    gld16(&Ks[(bufi) * KSB + c0 * 512 + lane * 8], K  + koff0 + kj_);         \
    gld16(&Ks[(bufi) * KSB + c1 * 512 + lane * 8], K  + koff1 + kj_);         \
    gld16(&Vt[(bufi) * VTB + c0 * 512 + lane * 8], Vg + voff0 + vj_);         \
    gld16(&Vt[(bufi) * VTB + c1 * 512 + lane * 8], Vg + voff1 + vj_);         \
  } while (0)

  // prologue: stage j0 and j0+1 (8 gld16/wave in flight)
  STG_KV(0, j0);
  if (j0 + 1 <= j1) STG_KV(1, j0 + 1);

  int cur = 0;
  for (int j = j0; j <= j1; ++j) {
    // counted wait: tile j's 4 ops retired; tile j+1's stay in flight
    asm volatile("" ::: "memory");
    if (j < j1) asm volatile("s_waitcnt vmcnt(4)" ::: "memory");
    else        asm volatile("s_waitcnt vmcnt(0)" ::: "memory");
    __builtin_amdgcn_s_barrier();
    asm volatile("" ::: "memory");

    if (j + 2 <= j1) {     // stage j+2 into tile j-1's buffer (safe: barrier)
      int nb = cur + 2; if (nb >= 3) nb -= 3;
      STG_KV(nb, j + 2);
    }

    const u16* ksb = &Ks[cur * KSB];
    const u16* vtb = &Vt[cur * VTB];

    // SWAPPED QK^T: sacc[hf][nt][r] = S[q = mcol + hf*16 + wv*32][
    // k = nt*16 + quad*4 + r]; K frags read once, used by both halves.
    floatx4 sacc[2][4] = {};
    __builtin_amdgcn_s_setprio(1);
#pragma unroll
    for (int nt = 0; nt < 4; ++nt) {
      const u16* kr = &ksb[(nt * 16 + mcol) * 64];
      bf16x8 kb0 = *(const bf16x8*)&kr[sl0];
      bf16x8 kb1 = *(const bf16x8*)&kr[sl0 ^ 32];
      sacc[0][nt] = __builtin_amdgcn_mfma_f32_16x16x32_bf16(kb0, qf[0][0], sacc[0][nt], 0, 0, 0);
      sacc[0][nt] = __builtin_amdgcn_mfma_f32_16x16x32_bf16(kb1, qf[0][1], sacc[0][nt], 0, 0, 0);
      sacc[1][nt] = __builtin_amdgcn_mfma_f32_16x16x32_bf16(kb0, qf[1][0], sacc[1][nt], 0, 0, 0);
      sacc[1][nt] = __builtin_amdgcn_mfma_f32_16x16x32_bf16(kb1, qf[1][1], sacc[1][nt], 0, 0, 0);
    }
    __builtin_amdgcn_s_setprio(0);

    const int dj = j - 2 * t;
    if (dj >= 0) {     // causal mask on the two diagonal k-tiles
#pragma unroll
      for (int hf = 0; hf < 2; ++hf) {
        const int klim = wv * 32 + hf * 16 + mcol - dj * 64;
#pragma unroll
        for (int nt = 0; nt < 4; ++nt)
#pragma unroll
          for (int r = 0; r < 4; ++r)
            if (nt * 16 + quad * 4 + r > klim) sacc[hf][nt][r] = -1e30f;
      }
    }

    // exp2 + pack + in-register redistribute -> PV A-frags (per half)
    bf16x8 pa[2][2];
#pragma unroll
    for (int hf = 0; hf < 2; ++hf) {
      unsigned w[4][2];
#pragma unroll
      for (int nt = 0; nt < 4; ++nt)
#pragma unroll
        for (int i = 0; i < 2; ++i)
          w[nt][i] = cvtpk(exp2f(sacc[hf][nt][2*i]), exp2f(sacc[hf][nt][2*i+1]));
      union { unsigned u[4]; bf16x8 v; } p0, p1;
#pragma unroll
      for (int i = 0; i < 2; ++i) {
        unsigned x = w[0][i], y = w[1][i];
        asm("v_permlane32_swap_b32 %0, %1" : "+v"(x), "+v"(y));
        asm("v_permlane16_swap_b32 %0, %1" : "+v"(x), "+v"(y));
        p0.u[i] = x; p0.u[i + 2] = y;
        unsigned x2 = w[2][i], y2 = w[3][i];
        asm("v_permlane32_swap_b32 %0, %1" : "+v"(x2), "+v"(y2));
        asm("v_permlane16_swap_b32 %0, %1" : "+v"(x2), "+v"(y2));
        p1.u[i] = x2; p1.u[i + 2] = y2;
      }
      pa[hf][0] = p0.v; pa[hf][1] = p1.v;
    }

    __builtin_amdgcn_s_setprio(1);
#pragma unroll
    for (int dt = 0; dt < 4; ++dt) {
      const u16* vr = &vtb[(dt * 16 + mcol) * 64];
      bf16x8 vb0 = *(const bf16x8*)&vr[sl0];
      bf16x8 vb1 = *(const bf16x8*)&vr[sl0 ^ 32];
      oacc[0][dt] = __builtin_amdgcn_mfma_f32_16x16x32_bf16(pa[0][0], vb0, oacc[0][dt], 0, 0, 0);
      oacc[0][dt] = __builtin_amdgcn_mfma_f32_16x16x32_bf16(pa[0][1], vb1, oacc[0][dt], 0, 0, 0);
      oacc[1][dt] = __builtin_amdgcn_mfma_f32_16x16x32_bf16(pa[1][0], vb0, oacc[1][dt], 0, 0, 0);
      oacc[1][dt] = __builtin_amdgcn_mfma_f32_16x16x32_bf16(pa[1][1], vb1, oacc[1][dt], 0, 0, 0);
    }
    // rowsum slots: constant ones B-frag (no LDS reads)
    oacc[0][4] = __builtin_amdgcn_mfma_f32_16x16x32_bf16(pa[0][0], vones, oacc[0][4], 0, 0, 0);
    oacc[0][4] = __builtin_amdgcn_mfma_f32_16x16x32_bf16(pa[0][1], vones, oacc[0][4], 0, 0, 0);
    oacc[1][4] = __builtin_amdgcn_mfma_f32_16x16x32_bf16(pa[1][0], vones, oacc[1][4], 0, 0, 0);
    oacc[1][4] = __builtin_amdgcn_mfma_f32_16x16x32_bf16(pa[1][1], vones, oacc[1][4], 0, 0, 0);
    __builtin_amdgcn_s_setprio(0);

    cur = (cur == 2) ? 0 : cur + 1;
  }

  if (!pm) {
    // direct store (unsplit tiles, t < 8)
#pragma unroll
    for (int hf = 0; hf < 2; ++hf) {
      float invl[4];
#pragma unroll
      for (int r = 0; r < 4; ++r)
        invl[r] = 1.f / __shfl(oacc[hf][4][r], lane & 48);
#pragma unroll
      for (int dt = 0; dt < 4; ++dt) {
        const int cc = h * D_ + dt * 16 + mcol;
#pragma unroll
        for (int r = 0; r < 4; ++r) {
          const int tg = t * 128 + wv * 32 + hf * 16 + quad * 4 + r;
          O[((size_t)b * T_ + tg) * C_ + cc] = f2bf(oacc[hf][dt][r] * invl[r]);
        }
      }
    }
  } else {
    // partial store: unnormalized f32 O (128x64) + l (pure-add merge later)
    float* op = OP + (size_t)ti * 8192;
#pragma unroll
    for (int hf = 0; hf < 2; ++hf) {
#pragma unroll
      for (int dt = 0; dt < 4; ++dt)
#pragma unroll
        for (int r = 0; r < 4; ++r)
          op[(wv * 32 + hf * 16 + quad * 4 + r) * 64 + dt * 16 + mcol] = oacc[hf][dt][r];
      if (mcol == 0) {
#pragma unroll
        for (int r = 0; r < 4; ++r)
          LP[ti * 128 + wv * 32 + hf * 16 + quad * 4 + r] = oacc[hf][4][r];
      }
    }
  }
}

// ---------------------------------------------------------------------------
// Merge the two k-chunks of each split q-tile (t = 8..15): O = (A+B)/(lA+lB).
// Grid 256 (32 bh x 8 tiles), 256 threads; thread = (row, 32-d-chunk).
// ---------------------------------------------------------------------------
__global__ __launch_bounds__(256) void attn_merge(
    const float* __restrict__ OP, const float* __restrict__ LP,
    u16* __restrict__ O)
{
  const int mb = blockIdx.x;
  const int bh = mb & 31, tt = mb >> 5;     // tt 0..7 -> t = 8+tt
  const int t = 8 + tt;
  const int ti0 = (bh * 8 + tt) * 2;
  const int b = bh >> 4, h = bh & (H_ - 1);
  const int row = threadIdx.x >> 1;         // 0..127
  const int dc  = (threadIdx.x & 1) * 32;

  const float l = LP[ti0 * 128 + row] + LP[(ti0 + 1) * 128 + row];
  const float inv = 1.f / l;
  const float* pa = OP + (size_t)ti0 * 8192 + row * 64 + dc;
  const float* pb = pa + 8192;

  const int tg = t * 128 + row;
  u16* o = O + ((size_t)b * T_ + tg) * C_ + h * D_ + dc;

  u16 tmp[32];
#pragma unroll
  for (int i = 0; i < 8; ++i) {
    const float4 a4 = ((const float4*)pa)[i];
    const float4 b4 = ((const float4*)pb)[i];
    tmp[i*4 + 0] = f2bf((a4.x + b4.x) * inv);
    tmp[i*4 + 1] = f2bf((a4.y + b4.y) * inv);
    tmp[i*4 + 2] = f2bf((a4.z + b4.z) * inv);
    tmp[i*4 + 3] = f2bf((a4.w + b4.w) * inv);
  }
#pragma unroll
  for (int i = 0; i < 4; ++i)
    ((uint4*)o)[i] = ((const uint4*)tmp)[i];
}

// ---------------------------------------------------------------------------
extern "C" void kernel_launch(void* const* d_in, const int* in_sizes, int n_in,
                              void* d_out, int out_size, void* d_ws, size_t ws_size,
                              hipStream_t stream) {
  const float* x  = (const float*)d_in[0];
  const float* Wq = (const float*)d_in[1];
  const float* bq = (const float*)d_in[2];
  const float* Wk = (const float*)d_in[3];
  const float* bk = (const float*)d_in[4];
  const float* Wv = (const float*)d_in[5];
  const float* bv = (const float*)d_in[6];
  const float* Wo = (const float*)d_in[7];
  const float* bo = (const float*)d_in[8];
  float* out = (float*)d_out;

  const size_t NX = (size_t)B_ * T_ * C_;  // 4M
  const size_t NW = (size_t)C_ * C_;       // 1M

  u16* xb  = (u16*)d_ws;
  u16* wqb = xb  + NX;        // weights contiguous (qkv GEMM indexes by z)
  u16* wkb = wqb + NW;
  u16* wvb = wkb + NW;
  u16* wob = wvb + NW;
  u16* q   = wob + NW;        // [B,H,T,D], pre-scaled log2-domain
  u16* k   = q   + NX;        // [B,H,T,D]
  u16* v   = k   + NX;        // [B,H,D,T]
  u16* ctx = v   + NX;        // [B,T,C]
  float* opart = (float*)(ctx + NX);           // 512 x 128x64 f32 = 16.8 MB
  float* lpart = opart + (size_t)512 * 8192;   // 512 x 128 f32

  cvt_all<<<dim3((NXF4 + 4 * NWF4) / 256), 256, 0, stream>>>(x, Wq, Wk, Wv, Wo, xb);

  gemm_qkv8<<<dim3(512), 512, 0, stream>>>(xb, wqb, bq, bk, bv, q, k, v);

  attn_flash<<<dim3(768), 256, 0, stream>>>(q, k, v, ctx, opart, lpart);

  attn_merge<<<dim3(256), 256, 0, stream>>>(opart, lpart, ctx);

  gemm_out<<<dim3(32, 8), 256, 0, stream>>>(ctx, wob, bo, out);
}